// Round 1
// baseline (381.115 us; speedup 1.0000x reference)
//
#include <hip/hip_runtime.h>

#define B_ 2
#define T_ 4096
#define D_ 256
#define H_ 8
#define DK_ 32
#define EPS_ 1e-5f

typedef __attribute__((ext_vector_type(8))) __bf16 bf16x8;
typedef __attribute__((ext_vector_type(4))) float f32x4;

__device__ inline unsigned short f2bf(float f) {
  unsigned int u = __float_as_uint(f);
  unsigned int r = (u + 0x7fffu + ((u >> 16) & 1u)) >> 16;  // RNE
  return (unsigned short)r;
}

__device__ inline f32x4 mfma16(bf16x8 a, bf16x8 b, f32x4 c) {
  return __builtin_amdgcn_mfma_f32_16x16x32_bf16(a, b, c, 0, 0, 0);
}

// ---- prep: fold BN into depthwise conv weights/bias ----
__global__ void prep_bn(const float* __restrict__ dw_w, const float* __restrict__ dw_b,
                        const float* __restrict__ gma, const float* __restrict__ bta,
                        const float* __restrict__ mu, const float* __restrict__ var,
                        float* __restrict__ wf, float* __restrict__ yb) {
  int i = blockIdx.x * blockDim.x + threadIdx.x;  // p*D + c, 768 total
  if (i >= 3 * D_) return;
  float s = gma[i] * rsqrtf(var[i] + EPS_);
  wf[i * 3 + 0] = dw_w[i * 3 + 0] * s;
  wf[i * 3 + 1] = dw_w[i * 3 + 1] * s;
  wf[i * 3 + 2] = dw_w[i * 3 + 2] * s;
  yb[i] = (dw_b[i] - mu[i]) * s + bta[i];
}

// ---- convert pointwise / output weights to bf16 ----
__global__ void cvt_w(const float* __restrict__ pw_w, const float* __restrict__ out_w,
                      unsigned short* __restrict__ Wb, unsigned short* __restrict__ Ob) {
  int i = blockIdx.x * blockDim.x + threadIdx.x;
  if (i < 3 * D_ * D_) Wb[i] = f2bf(pw_w[i]);
  if (i < D_ * D_) Ob[i] = f2bf(out_w[i]);
}

// ---- depthwise conv (K=3, pad same) + BN -> Y bf16 [3][B*T][D] ----
__global__ __launch_bounds__(256) void conv_bn(const float* __restrict__ x,
                                               const float* __restrict__ wf,
                                               const float* __restrict__ yb,
                                               unsigned short* __restrict__ Y) {
  int bt = blockIdx.x;        // b*T + t
  int c = threadIdx.x;        // 0..255
  int t = bt & (T_ - 1);
  const float* xp = x + (size_t)bt * D_ + c;
  float x0 = xp[0];
  float xm = (t > 0) ? xp[-D_] : 0.f;
  float xq = (t < T_ - 1) ? xp[D_] : 0.f;
#pragma unroll
  for (int p = 0; p < 3; ++p) {
    int pc = p * D_ + c;
    float y = fmaf(xm, wf[pc * 3 + 0],
              fmaf(x0, wf[pc * 3 + 1],
              fmaf(xq, wf[pc * 3 + 2], yb[pc])));
    Y[(size_t)p * (B_ * T_ * D_) + (size_t)bt * D_ + c] = f2bf(y);
  }
}

// ---- QKV pointwise GEMM: Z[p] = Y[p] (8192x256) * Wb[p]^T (256x256) + pw_b ----
// writes Q,K as [b][h][t][dk] bf16, V transposed as [b][h][dk][t] bf16
__global__ __launch_bounds__(256) void qkv_gemm(const unsigned short* __restrict__ Y,
                                                const unsigned short* __restrict__ Wb,
                                                const float* __restrict__ pw_b,
                                                unsigned short* __restrict__ Q,
                                                unsigned short* __restrict__ Kk,
                                                unsigned short* __restrict__ Vt) {
  int p = blockIdx.y;
  int m0 = blockIdx.x * 16;
  int wv = threadIdx.x >> 6;
  int lane = threadIdx.x & 63;
  int lm = lane & 15, g = lane >> 4;
  int n0 = wv * 64;
  const unsigned short* Yp = Y + (size_t)p * (B_ * T_ * D_);
  const unsigned short* Wp = Wb + (size_t)p * (D_ * D_);
  f32x4 acc[4] = {};
  for (int k0 = 0; k0 < D_; k0 += 32) {
    bf16x8 a = *reinterpret_cast<const bf16x8*>(Yp + (size_t)(m0 + lm) * D_ + k0 + 8 * g);
#pragma unroll
    for (int j = 0; j < 4; ++j) {
      bf16x8 b = *reinterpret_cast<const bf16x8*>(Wp + (size_t)(n0 + j * 16 + lm) * D_ + k0 + 8 * g);
      acc[j] = mfma16(a, b, acc[j]);
    }
  }
#pragma unroll
  for (int j = 0; j < 4; ++j) {
    int o = n0 + j * 16 + lm;
    float bias = pw_b[p * D_ + o];
    int h = o >> 5, dk = o & 31;
#pragma unroll
    for (int r = 0; r < 4; ++r) {
      int row = m0 + g * 4 + r;  // b*T + t
      int b = row >> 12, t = row & (T_ - 1);
      unsigned short bv = f2bf(acc[j][r] + bias);
      size_t bh = (size_t)(b * H_ + h);
      if (p == 0)
        Q[(bh * T_ + t) * DK_ + dk] = bv;
      else if (p == 1)
        Kk[(bh * T_ + t) * DK_ + dk] = bv;
      else
        Vt[(bh * DK_ + dk) * T_ + t] = bv;
    }
  }
}

// ---- flash attention: one wave per 16-row Q tile ----
__global__ __launch_bounds__(256) void attn(const unsigned short* __restrict__ Q,
                                            const unsigned short* __restrict__ Kk,
                                            const unsigned short* __restrict__ Vt,
                                            unsigned short* __restrict__ ctx) {
  __shared__ unsigned short P_lds[4][16][40];  // per-wave slice, stride 40 breaks conflicts
  int wv = threadIdx.x >> 6, lane = threadIdx.x & 63;
  int lm = lane & 15, g = lane >> 4;
  int wid = blockIdx.x * 4 + wv;  // 0..4095
  int bh = wid >> 8;              // 0..15  (b*H + h)
  int qt = wid & 255;
  int q0 = qt * 16;
  const unsigned short* Qh = Q + (size_t)bh * T_ * DK_;
  const unsigned short* Kh = Kk + (size_t)bh * T_ * DK_;
  const unsigned short* Vh = Vt + (size_t)bh * DK_ * T_;

  bf16x8 qf = *reinterpret_cast<const bf16x8*>(Qh + (size_t)(q0 + lm) * DK_ + 8 * g);
  const float scale = 0.17677669529663687f;  // 1/sqrt(32)
  float mrow[4], lrow[4];
  f32x4 acc0 = {}, acc1 = {};
#pragma unroll
  for (int r = 0; r < 4; ++r) { mrow[r] = -1e30f; lrow[r] = 0.f; }

  for (int k0 = 0; k0 < T_; k0 += 32) {
    bf16x8 kf0 = *reinterpret_cast<const bf16x8*>(Kh + (size_t)(k0 + lm) * DK_ + 8 * g);
    bf16x8 kf1 = *reinterpret_cast<const bf16x8*>(Kh + (size_t)(k0 + 16 + lm) * DK_ + 8 * g);
    f32x4 z = {};
    f32x4 s0 = mfma16(qf, kf0, z);
    f32x4 s1 = mfma16(qf, kf1, z);
    float al[4];
#pragma unroll
    for (int r = 0; r < 4; ++r) {
      float a = s0[r] * scale, b = s1[r] * scale;
      float mx = fmaxf(a, b);
      mx = fmaxf(mx, __shfl_xor(mx, 1));
      mx = fmaxf(mx, __shfl_xor(mx, 2));
      mx = fmaxf(mx, __shfl_xor(mx, 4));
      mx = fmaxf(mx, __shfl_xor(mx, 8));
      float mn = fmaxf(mrow[r], mx);
      al[r] = __expf(mrow[r] - mn);
      mrow[r] = mn;
      float p0 = __expf(a - mn);
      float p1 = __expf(b - mn);
      float rs = p0 + p1;
      rs += __shfl_xor(rs, 1);
      rs += __shfl_xor(rs, 2);
      rs += __shfl_xor(rs, 4);
      rs += __shfl_xor(rs, 8);
      lrow[r] = lrow[r] * al[r] + rs;
      P_lds[wv][g * 4 + r][lm] = f2bf(p0);
      P_lds[wv][g * 4 + r][16 + lm] = f2bf(p1);
    }
    __syncthreads();
    bf16x8 pf = *reinterpret_cast<const bf16x8*>(&P_lds[wv][lm][8 * g]);
    bf16x8 vf0 = *reinterpret_cast<const bf16x8*>(Vh + (size_t)lm * T_ + k0 + 8 * g);
    bf16x8 vf1 = *reinterpret_cast<const bf16x8*>(Vh + (size_t)(16 + lm) * T_ + k0 + 8 * g);
#pragma unroll
    for (int r = 0; r < 4; ++r) { acc0[r] *= al[r]; acc1[r] *= al[r]; }
    acc0 = mfma16(pf, vf0, acc0);
    acc1 = mfma16(pf, vf1, acc1);
  }

  int b = bh >> 3, h = bh & 7;
#pragma unroll
  for (int r = 0; r < 4; ++r) {
    int t = q0 + g * 4 + r;
    float inv = 1.f / lrow[r];
    size_t base = ((size_t)(b * T_ + t)) * D_ + h * DK_;
    ctx[base + lm] = f2bf(acc0[r] * inv);
    ctx[base + 16 + lm] = f2bf(acc1[r] * inv);
  }
}

// ---- output projection: out = ctx (8192x256) * Ob^T (256x256) + out_b, f32 out ----
__global__ __launch_bounds__(256) void out_gemm(const unsigned short* __restrict__ ctx,
                                                const unsigned short* __restrict__ Ob,
                                                const float* __restrict__ out_b,
                                                float* __restrict__ out) {
  int m0 = blockIdx.x * 16;
  int wv = threadIdx.x >> 6, lane = threadIdx.x & 63;
  int lm = lane & 15, g = lane >> 4;
  int n0 = wv * 64;
  f32x4 acc[4] = {};
  for (int k0 = 0; k0 < D_; k0 += 32) {
    bf16x8 a = *reinterpret_cast<const bf16x8*>(ctx + (size_t)(m0 + lm) * D_ + k0 + 8 * g);
#pragma unroll
    for (int j = 0; j < 4; ++j) {
      bf16x8 b = *reinterpret_cast<const bf16x8*>(Ob + (size_t)(n0 + j * 16 + lm) * D_ + k0 + 8 * g);
      acc[j] = mfma16(a, b, acc[j]);
    }
  }
#pragma unroll
  for (int j = 0; j < 4; ++j) {
    int o = n0 + j * 16 + lm;
    float bias = out_b[o];
#pragma unroll
    for (int r = 0; r < 4; ++r) {
      int row = m0 + g * 4 + r;
      out[(size_t)row * D_ + o] = acc[j][r] + bias;
    }
  }
}

extern "C" void kernel_launch(void* const* d_in, const int* in_sizes, int n_in,
                              void* d_out, int out_size, void* d_ws, size_t ws_size,
                              hipStream_t stream) {
  const float* x = (const float*)d_in[0];
  const float* dw_w = (const float*)d_in[1];
  const float* dw_b = (const float*)d_in[2];
  const float* gma = (const float*)d_in[3];
  const float* bta = (const float*)d_in[4];
  const float* mu = (const float*)d_in[5];
  const float* var = (const float*)d_in[6];
  const float* pw_w = (const float*)d_in[7];
  const float* pw_b = (const float*)d_in[8];
  const float* out_w = (const float*)d_in[9];
  const float* out_b = (const float*)d_in[10];
  float* out = (float*)d_out;

  char* ws = (char*)d_ws;
  size_t off = 0;
  auto alloc = [&](size_t bytes) -> void* {
    void* ptr = (void*)(ws + off);
    off += (bytes + 255) & ~(size_t)255;
    return ptr;
  };
  float* wf = (float*)alloc(3 * 256 * 3 * 4);
  float* yb = (float*)alloc(3 * 256 * 4);
  unsigned short* Wb = (unsigned short*)alloc((size_t)3 * 256 * 256 * 2);
  unsigned short* Ob = (unsigned short*)alloc((size_t)256 * 256 * 2);
  unsigned short* Y = (unsigned short*)alloc((size_t)3 * 8192 * 256 * 2);
  unsigned short* Q = (unsigned short*)alloc((size_t)16 * 4096 * 32 * 2);
  unsigned short* Kk = (unsigned short*)alloc((size_t)16 * 4096 * 32 * 2);
  unsigned short* Vt = (unsigned short*)alloc((size_t)16 * 32 * 4096 * 2);
  unsigned short* ctx = (unsigned short*)alloc((size_t)8192 * 256 * 2);

  hipLaunchKernelGGL(prep_bn, dim3(3), dim3(256), 0, stream, dw_w, dw_b, gma, bta, mu, var, wf, yb);
  hipLaunchKernelGGL(cvt_w, dim3(768), dim3(256), 0, stream, pw_w, out_w, Wb, Ob);
  hipLaunchKernelGGL(conv_bn, dim3(8192), dim3(256), 0, stream, x, wf, yb, Y);
  hipLaunchKernelGGL(qkv_gemm, dim3(512, 3), dim3(256), 0, stream, Y, Wb, pw_b, Q, Kk, Vt);
  hipLaunchKernelGGL(attn, dim3(1024), dim3(256), 0, stream, Q, Kk, Vt, ctx);
  hipLaunchKernelGGL(out_gemm, dim3(512), dim3(256), 0, stream, ctx, Ob, out_b, out);
}

// Round 3
// 301.603 us; speedup vs baseline: 1.2636x; 1.2636x over previous
//
#include <hip/hip_runtime.h>

#define B_ 2
#define T_ 4096
#define D_ 256
#define H_ 8
#define DK_ 32
#define EPS_ 1e-5f

typedef __attribute__((ext_vector_type(8))) __bf16 bf16x8;
typedef __attribute__((ext_vector_type(4))) float f32x4;

// 1/sqrt(32) * log2(e): folded into Q so softmax uses raw v_exp_f32 (2^x)
#define QSCALE 0.25503497f

__device__ inline unsigned short f2bf(float f) {
  unsigned int u = __float_as_uint(f);
  unsigned int r = (u + 0x7fffu + ((u >> 16) & 1u)) >> 16;  // RNE
  return (unsigned short)r;
}

__device__ inline f32x4 mfma16(bf16x8 a, bf16x8 b, f32x4 c) {
  return __builtin_amdgcn_mfma_f32_16x16x32_bf16(a, b, c, 0, 0, 0);
}

// ---- prep: fold BN into depthwise conv weights/bias ----
__global__ void prep_bn(const float* __restrict__ dw_w, const float* __restrict__ dw_b,
                        const float* __restrict__ gma, const float* __restrict__ bta,
                        const float* __restrict__ mu, const float* __restrict__ var,
                        float* __restrict__ wf, float* __restrict__ yb) {
  int i = blockIdx.x * blockDim.x + threadIdx.x;  // p*D + c, 768 total
  if (i >= 3 * D_) return;
  float s = gma[i] * rsqrtf(var[i] + EPS_);
  wf[i * 3 + 0] = dw_w[i * 3 + 0] * s;
  wf[i * 3 + 1] = dw_w[i * 3 + 1] * s;
  wf[i * 3 + 2] = dw_w[i * 3 + 2] * s;
  yb[i] = (dw_b[i] - mu[i]) * s + bta[i];
}

// ---- convert pointwise / output weights to bf16 ----
__global__ void cvt_w(const float* __restrict__ pw_w, const float* __restrict__ out_w,
                      unsigned short* __restrict__ Wb, unsigned short* __restrict__ Ob) {
  int i = blockIdx.x * blockDim.x + threadIdx.x;
  if (i < 3 * D_ * D_) Wb[i] = f2bf(pw_w[i]);
  if (i < D_ * D_) Ob[i] = f2bf(out_w[i]);
}

// ---- depthwise conv (K=3, pad same) + BN -> Y bf16 [3][B*T][D] ----
__global__ __launch_bounds__(256) void conv_bn(const float* __restrict__ x,
                                               const float* __restrict__ wf,
                                               const float* __restrict__ yb,
                                               unsigned short* __restrict__ Y) {
  int bt = blockIdx.x;        // b*T + t
  int c = threadIdx.x;        // 0..255
  int t = bt & (T_ - 1);
  const float* xp = x + (size_t)bt * D_ + c;
  float x0 = xp[0];
  float xm = (t > 0) ? xp[-D_] : 0.f;
  float xq = (t < T_ - 1) ? xp[D_] : 0.f;
#pragma unroll
  for (int p = 0; p < 3; ++p) {
    int pc = p * D_ + c;
    float y = fmaf(xm, wf[pc * 3 + 0],
              fmaf(x0, wf[pc * 3 + 1],
              fmaf(xq, wf[pc * 3 + 2], yb[pc])));
    Y[(size_t)p * (B_ * T_ * D_) + (size_t)bt * D_ + c] = f2bf(y);
  }
}

// ---- QKV pointwise GEMM: Z[p] = Y[p] (8192x256) * Wb[p]^T (256x256) + pw_b ----
// writes Q (pre-scaled by 1/sqrt(dk)*log2e) and K as [b][h][t][dk], V transposed [b][h][dk][t]
__global__ __launch_bounds__(256) void qkv_gemm(const unsigned short* __restrict__ Y,
                                                const unsigned short* __restrict__ Wb,
                                                const float* __restrict__ pw_b,
                                                unsigned short* __restrict__ Q,
                                                unsigned short* __restrict__ Kk,
                                                unsigned short* __restrict__ Vt) {
  int p = blockIdx.y;
  int m0 = blockIdx.x * 16;
  int wv = threadIdx.x >> 6;
  int lane = threadIdx.x & 63;
  int lm = lane & 15, g = lane >> 4;
  int n0 = wv * 64;
  const unsigned short* Yp = Y + (size_t)p * (B_ * T_ * D_);
  const unsigned short* Wp = Wb + (size_t)p * (D_ * D_);
  f32x4 acc[4] = {};
  for (int k0 = 0; k0 < D_; k0 += 32) {
    bf16x8 a = *reinterpret_cast<const bf16x8*>(Yp + (size_t)(m0 + lm) * D_ + k0 + 8 * g);
#pragma unroll
    for (int j = 0; j < 4; ++j) {
      bf16x8 b = *reinterpret_cast<const bf16x8*>(Wp + (size_t)(n0 + j * 16 + lm) * D_ + k0 + 8 * g);
      acc[j] = mfma16(a, b, acc[j]);
    }
  }
  float scl = (p == 0) ? QSCALE : 1.0f;
#pragma unroll
  for (int j = 0; j < 4; ++j) {
    int o = n0 + j * 16 + lm;
    float bias = pw_b[p * D_ + o];
    int h = o >> 5, dk = o & 31;
#pragma unroll
    for (int r = 0; r < 4; ++r) {
      int row = m0 + g * 4 + r;  // b*T + t
      int b = row >> 12, t = row & (T_ - 1);
      unsigned short bv = f2bf((acc[j][r] + bias) * scl);
      size_t bh = (size_t)(b * H_ + h);
      if (p == 0)
        Q[(bh * T_ + t) * DK_ + dk] = bv;
      else if (p == 1)
        Kk[(bh * T_ + t) * DK_ + dk] = bv;
      else
        Vt[(bh * DK_ + dk) * T_ + t] = bv;
    }
  }
}

// ---- flash attention: swapped QK^T, fully in-register softmax, no LDS ----
// One wave per 16 q-rows. Scores via mfma(K,Q): lane(lm,g) holds q-row lm.
// K rows loaded permuted (ra, ra+4) so each lane's P lands directly in
// PV A-fragment layout (keys 8g..8g+7) with ZERO cross-lane moves.
__global__ __launch_bounds__(256) void attn(const unsigned short* __restrict__ Q,
                                            const unsigned short* __restrict__ Kk,
                                            const unsigned short* __restrict__ Vt,
                                            unsigned short* __restrict__ ctx) {
  int wv = threadIdx.x >> 6, lane = threadIdx.x & 63;
  int lm = lane & 15, g = lane >> 4;
  int wid = blockIdx.x * 4 + wv;  // 0..4095
  int bh = wid >> 8;              // b*H + h
  int qt = wid & 255;
  int q0 = qt * 16;
  const unsigned short* Qh = Q + (size_t)bh * (T_ * DK_);
  const unsigned short* Kh = Kk + (size_t)bh * (T_ * DK_);
  const unsigned short* Vh = Vt + (size_t)bh * (DK_ * T_);

  // Q fragment (B operand): lane holds Q[q0+lm][8g..8g+7]
  bf16x8 qf = *reinterpret_cast<const bf16x8*>(Qh + (size_t)(q0 + lm) * DK_ + 8 * g);

  const int ra = 8 * (lm >> 2) + (lm & 3);  // permuted K row for score A-frag
  const unsigned short* Kp = Kh + (size_t)ra * DK_ + 8 * g;
  const unsigned short* Vp = Vh + (size_t)lm * T_ + 8 * g;

  float mrow = -1e30f, lrow = 0.f;
  f32x4 acc_lo = {}, acc_hi = {};

  for (int k0 = 0; k0 < T_; k0 += 64) {
    bf16x8 kA0 = *reinterpret_cast<const bf16x8*>(Kp + (size_t)k0 * DK_);
    bf16x8 kA1 = *reinterpret_cast<const bf16x8*>(Kp + (size_t)(k0 + 4) * DK_);
    bf16x8 kB0 = *reinterpret_cast<const bf16x8*>(Kp + (size_t)(k0 + 32) * DK_);
    bf16x8 kB1 = *reinterpret_cast<const bf16x8*>(Kp + (size_t)(k0 + 36) * DK_);
    bf16x8 v00 = *reinterpret_cast<const bf16x8*>(Vp + k0);
    bf16x8 v10 = *reinterpret_cast<const bf16x8*>(Vp + k0 + 32);
    bf16x8 v01 = *reinterpret_cast<const bf16x8*>(Vp + 16 * T_ + k0);
    bf16x8 v11 = *reinterpret_cast<const bf16x8*>(Vp + 16 * T_ + k0 + 32);

    f32x4 z = {};
    f32x4 sA0 = mfma16(kA0, qf, z);  // keys k0+8g+r
    f32x4 sA1 = mfma16(kA1, qf, z);  // keys k0+8g+4+r
    f32x4 sB0 = mfma16(kB0, qf, z);  // keys k0+32+8g+r
    f32x4 sB1 = mfma16(kB1, qf, z);  // keys k0+32+8g+4+r

    float mx = fmaxf(
        fmaxf(fmaxf(fmaxf(sA0[0], sA0[1]), fmaxf(sA0[2], sA0[3])),
              fmaxf(fmaxf(sA1[0], sA1[1]), fmaxf(sA1[2], sA1[3]))),
        fmaxf(fmaxf(fmaxf(sB0[0], sB0[1]), fmaxf(sB0[2], sB0[3])),
              fmaxf(fmaxf(sB1[0], sB1[1]), fmaxf(sB1[2], sB1[3]))));
    mx = fmaxf(mx, __shfl_xor(mx, 16));
    mx = fmaxf(mx, __shfl_xor(mx, 32));

    // defer-max (T13): only rescale when the row max grew by >8 (log2 units)
    if (!__all(mx <= mrow + 8.f)) {
      float mn = fmaxf(mrow, mx);
      float al = __builtin_amdgcn_exp2f(mrow - mn);
      mrow = mn;
      float al0 = __shfl(al, 4 * g + 0);
      float al1 = __shfl(al, 4 * g + 1);
      float al2 = __shfl(al, 4 * g + 2);
      float al3 = __shfl(al, 4 * g + 3);
      lrow *= al;
      acc_lo[0] *= al0; acc_hi[0] *= al0;
      acc_lo[1] *= al1; acc_hi[1] *= al1;
      acc_lo[2] *= al2; acc_hi[2] *= al2;
      acc_lo[3] *= al3; acc_hi[3] *= al3;
    }

    float pA0 = __builtin_amdgcn_exp2f(sA0[0] - mrow);
    float pA1 = __builtin_amdgcn_exp2f(sA0[1] - mrow);
    float pA2 = __builtin_amdgcn_exp2f(sA0[2] - mrow);
    float pA3 = __builtin_amdgcn_exp2f(sA0[3] - mrow);
    float pA4 = __builtin_amdgcn_exp2f(sA1[0] - mrow);
    float pA5 = __builtin_amdgcn_exp2f(sA1[1] - mrow);
    float pA6 = __builtin_amdgcn_exp2f(sA1[2] - mrow);
    float pA7 = __builtin_amdgcn_exp2f(sA1[3] - mrow);
    float pB0 = __builtin_amdgcn_exp2f(sB0[0] - mrow);
    float pB1 = __builtin_amdgcn_exp2f(sB0[1] - mrow);
    float pB2 = __builtin_amdgcn_exp2f(sB0[2] - mrow);
    float pB3 = __builtin_amdgcn_exp2f(sB0[3] - mrow);
    float pB4 = __builtin_amdgcn_exp2f(sB1[0] - mrow);
    float pB5 = __builtin_amdgcn_exp2f(sB1[1] - mrow);
    float pB6 = __builtin_amdgcn_exp2f(sB1[2] - mrow);
    float pB7 = __builtin_amdgcn_exp2f(sB1[3] - mrow);

    bf16x8 pfA, pfB;
    pfA[0] = (__bf16)pA0; pfA[1] = (__bf16)pA1; pfA[2] = (__bf16)pA2; pfA[3] = (__bf16)pA3;
    pfA[4] = (__bf16)pA4; pfA[5] = (__bf16)pA5; pfA[6] = (__bf16)pA6; pfA[7] = (__bf16)pA7;
    pfB[0] = (__bf16)pB0; pfB[1] = (__bf16)pB1; pfB[2] = (__bf16)pB2; pfB[3] = (__bf16)pB3;
    pfB[4] = (__bf16)pB4; pfB[5] = (__bf16)pB5; pfB[6] = (__bf16)pB6; pfB[7] = (__bf16)pB7;

    float rs = (((pA0 + pA1) + (pA2 + pA3)) + ((pA4 + pA5) + (pA6 + pA7))) +
               (((pB0 + pB1) + (pB2 + pB3)) + ((pB4 + pB5) + (pB6 + pB7)));
    rs += __shfl_xor(rs, 16);
    rs += __shfl_xor(rs, 32);
    lrow += rs;

    acc_lo = mfma16(pfA, v00, acc_lo);
    acc_lo = mfma16(pfB, v10, acc_lo);
    acc_hi = mfma16(pfA, v01, acc_hi);
    acc_hi = mfma16(pfB, v11, acc_hi);
  }

  float inv = 1.f / lrow;  // valid for q-row lm (replicated across g)
  float i0 = __shfl(inv, 4 * g + 0);
  float i1 = __shfl(inv, 4 * g + 1);
  float i2 = __shfl(inv, 4 * g + 2);
  float i3 = __shfl(inv, 4 * g + 3);
  int b = bh >> 3, h = bh & 7;
  // PV output: lane(lm,g) reg r -> q = q0+4g+r, d = lm / lm+16
  {
    int t = q0 + 4 * g;
    size_t base = ((size_t)(b * T_ + t)) * D_ + h * DK_;
    ctx[base + lm] = f2bf(acc_lo[0] * i0);
    ctx[base + 16 + lm] = f2bf(acc_hi[0] * i0);
    base += D_;
    ctx[base + lm] = f2bf(acc_lo[1] * i1);
    ctx[base + 16 + lm] = f2bf(acc_hi[1] * i1);
    base += D_;
    ctx[base + lm] = f2bf(acc_lo[2] * i2);
    ctx[base + 16 + lm] = f2bf(acc_hi[2] * i2);
    base += D_;
    ctx[base + lm] = f2bf(acc_lo[3] * i3);
    ctx[base + 16 + lm] = f2bf(acc_hi[3] * i3);
  }
}

// ---- output projection: out = ctx (8192x256) * Ob^T (256x256) + out_b, f32 out ----
__global__ __launch_bounds__(256) void out_gemm(const unsigned short* __restrict__ ctx,
                                                const unsigned short* __restrict__ Ob,
                                                const float* __restrict__ out_b,
                                                float* __restrict__ out) {
  int m0 = blockIdx.x * 16;
  int wv = threadIdx.x >> 6, lane = threadIdx.x & 63;
  int lm = lane & 15, g = lane >> 4;
  int n0 = wv * 64;
  f32x4 acc[4] = {};
  for (int k0 = 0; k0 < D_; k0 += 32) {
    bf16x8 a = *reinterpret_cast<const bf16x8*>(ctx + (size_t)(m0 + lm) * D_ + k0 + 8 * g);
#pragma unroll
    for (int j = 0; j < 4; ++j) {
      bf16x8 b = *reinterpret_cast<const bf16x8*>(Ob + (size_t)(n0 + j * 16 + lm) * D_ + k0 + 8 * g);
      acc[j] = mfma16(a, b, acc[j]);
    }
  }
#pragma unroll
  for (int j = 0; j < 4; ++j) {
    int o = n0 + j * 16 + lm;
    float bias = out_b[o];
#pragma unroll
    for (int r = 0; r < 4; ++r) {
      int row = m0 + g * 4 + r;
      out[(size_t)row * D_ + o] = acc[j][r] + bias;
    }
  }
}

extern "C" void kernel_launch(void* const* d_in, const int* in_sizes, int n_in,
                              void* d_out, int out_size, void* d_ws, size_t ws_size,
                              hipStream_t stream) {
  const float* x = (const float*)d_in[0];
  const float* dw_w = (const float*)d_in[1];
  const float* dw_b = (const float*)d_in[2];
  const float* gma = (const float*)d_in[3];
  const float* bta = (const float*)d_in[4];
  const float* mu = (const float*)d_in[5];
  const float* var = (const float*)d_in[6];
  const float* pw_w = (const float*)d_in[7];
  const float* pw_b = (const float*)d_in[8];
  const float* out_w = (const float*)d_in[9];
  const float* out_b = (const float*)d_in[10];
  float* out = (float*)d_out;

  char* ws = (char*)d_ws;
  size_t off = 0;
  auto alloc = [&](size_t bytes) -> void* {
    void* ptr = (void*)(ws + off);
    off += (bytes + 255) & ~(size_t)255;
    return ptr;
  };
  float* wf = (float*)alloc(3 * 256 * 3 * 4);
  float* yb = (float*)alloc(3 * 256 * 4);
  unsigned short* Wb = (unsigned short*)alloc((size_t)3 * 256 * 256 * 2);
  unsigned short* Ob = (unsigned short*)alloc((size_t)256 * 256 * 2);
  unsigned short* Y = (unsigned short*)alloc((size_t)3 * 8192 * 256 * 2);
  unsigned short* Q = (unsigned short*)alloc((size_t)16 * 4096 * 32 * 2);
  unsigned short* Kk = (unsigned short*)alloc((size_t)16 * 4096 * 32 * 2);
  unsigned short* Vt = (unsigned short*)alloc((size_t)16 * 32 * 4096 * 2);
  unsigned short* ctx = (unsigned short*)alloc((size_t)8192 * 256 * 2);

  hipLaunchKernelGGL(prep_bn, dim3(3), dim3(256), 0, stream, dw_w, dw_b, gma, bta, mu, var, wf, yb);
  hipLaunchKernelGGL(cvt_w, dim3(768), dim3(256), 0, stream, pw_w, out_w, Wb, Ob);
  hipLaunchKernelGGL(conv_bn, dim3(8192), dim3(256), 0, stream, x, wf, yb, Y);
  hipLaunchKernelGGL(qkv_gemm, dim3(512, 3), dim3(256), 0, stream, Y, Wb, pw_b, Q, Kk, Vt);
  hipLaunchKernelGGL(attn, dim3(1024), dim3(256), 0, stream, Q, Kk, Vt, ctx);
  hipLaunchKernelGGL(out_gemm, dim3(512), dim3(256), 0, stream, ctx, Ob, out_b, out);
}